// Round 5
// baseline (252.836 us; speedup 1.0000x reference)
//
#include <hip/hip_runtime.h>

// ---------------------------------------------------------------------------
// MHA: out = (softmax(split(XqWq^T+bq) @ split(XkWk^T+bk)^T / 8) @ split(XvWv^T+bv)) @ Wo^T + bo
// B=2, S=2048, D=1024, H=16, Dk=64. fp32 I/O; bf16 MFMA compute.
// R5: BK=32 dbuf GEMMs at 6/4 blocks-per-CU; attn QBLK=32/wave (128 rows/blk).
// ---------------------------------------------------------------------------

typedef short bf16x8 __attribute__((ext_vector_type(8)));
typedef float f32x4 __attribute__((ext_vector_type(4)));

#define D_MODEL 1024
#define NHEAD 16
#define DK 64
#define BB 2
#define SS 2048
#define MROWS (BB * SS) /* 4096 */
#define C1 0.18033688011112042f /* (1/8)*log2(e) */

__device__ __forceinline__ unsigned short f2bf(float f) {
  unsigned u = __builtin_bit_cast(unsigned, f);
  u += 0x7fffu + ((u >> 16) & 1u);  // RNE
  return (unsigned short)(u >> 16);
}
__device__ __forceinline__ unsigned pack2(float a, float b) {
  return (unsigned)f2bf(a) | ((unsigned)f2bf(b) << 16);
}
__device__ __forceinline__ unsigned cvtpk(float lo, float hi) {
  unsigned r;
  asm("v_cvt_pk_bf16_f32 %0, %1, %2" : "=v"(r) : "v"(lo), "v"(hi));
  return r;
}
__device__ __forceinline__ float max3f(float a, float b, float c) {
  float d;
  asm("v_max3_f32 %0, %1, %2, %3" : "=v"(d) : "v"(a), "v"(b), "v"(c));
  return d;
}

typedef __attribute__((address_space(3))) unsigned int as3u;
typedef const __attribute__((address_space(1))) unsigned int as1u;
__device__ __forceinline__ void gload16(void* lds, const void* g) {
  __builtin_amdgcn_global_load_lds((as1u*)g, (as3u*)lds, 16, 0, 0);
}

// ---------------------------------------------------------------------------
// fp32 -> bf16 conversion pass
// ---------------------------------------------------------------------------
struct CvtArgs {
  const float* s[7];
  unsigned short* d[7];
  int n8[7];
};

__global__ __launch_bounds__(256) void convert_bf16(CvtArgs a) {
  const int slot = blockIdx.y;
  const float* __restrict__ s = a.s[slot];
  unsigned short* __restrict__ d = a.d[slot];
  const int n8 = a.n8[slot];
  for (int i = blockIdx.x * 256 + threadIdx.x; i < n8; i += gridDim.x * 256) {
    const size_t off = (size_t)i * 8;
    const float4 v0 = *(const float4*)&s[off];
    const float4 v1 = *(const float4*)&s[off + 4];
    uint4 p;
    p.x = pack2(v0.x, v0.y); p.y = pack2(v0.z, v0.w);
    p.z = pack2(v1.x, v1.y); p.w = pack2(v1.z, v1.w);
    *(uint4*)&d[off] = p;
  }
}

// ---------------------------------------------------------------------------
// bf16 GEMM core, BK=32 double-buffered (1 barrier per K-step).
// C = A * B^T + bias, K=1024. MODE 0: bf16 C (scaled). MODE 1: f32 C.
// MODE 2: C^T -> vT[b*1024+col][s] via LDS-bounce transpose.
// 4 waves (2x2). Stage swizzle: LDS slot s holds global col-group s^((row>>1)&3);
// read of col-group l4 uses slot ((r>>1)&3)^l4 -> <=2-way bank aliasing.
// ---------------------------------------------------------------------------
template <int BM, int BN, int MODE>
__device__ __forceinline__ void gemm_core(unsigned short* smem,
                                          const unsigned short* __restrict__ A,
                                          const unsigned short* __restrict__ B,
                                          const float* __restrict__ bias,
                                          float scale, float* __restrict__ Cf,
                                          unsigned short* __restrict__ Cb) {
  const int LDSZ = (BM + BN) * 32;  // elements per buffer
  const int tid = threadIdx.x;
  const int lane = tid & 63, w = tid >> 6;
  const int wm = w >> 1, wn = w & 1;
  const int l15 = lane & 15, l4 = lane >> 4;
  const int bm = blockIdx.y, bn = blockIdx.x;
  const int MF = BM / 32, NF = BN / 32;

  auto stage = [&](unsigned short* dst, int k0) {
    unsigned short* Asb = dst;
    unsigned short* Bsb = dst + BM * 32;
#pragma unroll
    for (int i = 0; i < BM / 64; ++i) {
      const int flat = i * 256 + tid;
      const int row = flat >> 2, gl = flat & 3;
      const int gs = (gl ^ ((row >> 1) & 3)) * 8;
      gload16(&Asb[flat * 8], &A[(size_t)(bm * BM + row) * D_MODEL + k0 + gs]);
    }
#pragma unroll
    for (int i = 0; i < BN / 64; ++i) {
      const int flat = i * 256 + tid;
      const int row = flat >> 2, gl = flat & 3;
      const int gs = (gl ^ ((row >> 1) & 3)) * 8;
      gload16(&Bsb[flat * 8], &B[(size_t)(bn * BN + row) * D_MODEL + k0 + gs]);
    }
  };

  f32x4 acc[MF][NF];
#pragma unroll
  for (int m = 0; m < MF; ++m)
#pragma unroll
    for (int n = 0; n < NF; ++n) acc[m][n] = (f32x4){0.f, 0.f, 0.f, 0.f};

  stage(smem, 0);
  __syncthreads();
  int cur = 0;
  for (int k0 = 0; k0 < D_MODEL; k0 += 32) {
    if (k0 + 32 < D_MODEL) stage(smem + (cur ^ 1) * LDSZ, k0 + 32);
    unsigned short* As = smem + cur * LDSZ;
    unsigned short* Bs = As + BM * 32;
    bf16x8 af[MF], bf[NF];
#pragma unroll
    for (int m = 0; m < MF; ++m) {
      const int r = wm * (BM / 2) + m * 16 + l15;
      af[m] = *(const bf16x8*)&As[r * 32 + ((((r >> 1) & 3) ^ l4) << 3)];
    }
#pragma unroll
    for (int n = 0; n < NF; ++n) {
      const int r = wn * (BN / 2) + n * 16 + l15;
      bf[n] = *(const bf16x8*)&Bs[r * 32 + ((((r >> 1) & 3) ^ l4) << 3)];
    }
#pragma unroll
    for (int m = 0; m < MF; ++m)
#pragma unroll
      for (int n = 0; n < NF; ++n)
        acc[m][n] = __builtin_amdgcn_mfma_f32_16x16x32_bf16(af[m], bf[n], acc[m][n], 0, 0, 0);
    __syncthreads();
    cur ^= 1;
  }

  if (MODE != 2) {
#pragma unroll
    for (int m = 0; m < MF; ++m)
#pragma unroll
      for (int n = 0; n < NF; ++n) {
        const int col = bn * BN + wn * (BN / 2) + n * 16 + l15;
        const float bv = bias[col];
#pragma unroll
        for (int r = 0; r < 4; ++r) {
          const int row = bm * BM + wm * (BM / 2) + m * 16 + l4 * 4 + r;
          const float v = (acc[m][n][r] + bv) * scale;
          if (MODE == 0) Cb[(size_t)row * D_MODEL + col] = f2bf(v);
          else           Cf[(size_t)row * D_MODEL + col] = v;
        }
      }
  } else {
    // Transpose through LDS: T[cl][rl], pitch BM*2 B, group swizzle (rl>>3)^(cl&7)
    unsigned short* T = smem;
#pragma unroll
    for (int m = 0; m < MF; ++m)
#pragma unroll
      for (int n = 0; n < NF; ++n) {
        const int cl = wn * (BN / 2) + n * 16 + l15;
        const float bv = bias[bn * BN + cl];
#pragma unroll
        for (int r = 0; r < 4; ++r) {
          const int rl = wm * (BM / 2) + m * 16 + l4 * 4 + r;
          const int byte = cl * (BM * 2) + ((((rl >> 3) ^ (cl & 7))) << 4) + ((rl & 7) << 1);
          *(unsigned short*)((char*)T + byte) = f2bf(acc[m][n][r] + bv);
        }
      }
    __syncthreads();
#pragma unroll
    for (int c = 0; c < BN * BM / 8 / 256; ++c) {
      const int chunk = c * 256 + tid;
      const int cl = chunk >> 3, rl0 = (chunk & 7) * 8;
      const int byte = cl * (BM * 2) + (((rl0 >> 3) ^ (cl & 7)) << 4);
      const uint4 val = *(const uint4*)((const char*)T + byte);
      const int gcol = bn * BN + cl;
      const int bb = (bm * BM) >> 11;
      const int s = ((bm * BM) & 2047) + rl0;
      *(uint4*)&Cb[(size_t)(bb * 1024 + gcol) * SS + s] = val;
    }
  }
}

__global__ __launch_bounds__(256, 6) void gemm_qkv(
    const unsigned short* __restrict__ Xq, const unsigned short* __restrict__ Xk,
    const unsigned short* __restrict__ Xv,
    const unsigned short* __restrict__ Wq, const float* __restrict__ bq,
    const unsigned short* __restrict__ Wk, const float* __restrict__ bk,
    const unsigned short* __restrict__ Wv, const float* __restrict__ bv,
    unsigned short* __restrict__ q, unsigned short* __restrict__ k,
    unsigned short* __restrict__ vT) {
  __shared__ __align__(16) unsigned short smem[2 * (64 + 128) * 32];  // 24 KB
  const int z = blockIdx.z;
  if (z == 0) {
    gemm_core<64, 128, 0>(smem, Xq, Wq, bq, C1, nullptr, q);  // q pre-scaled
  } else if (z == 1) {
    gemm_core<64, 128, 0>(smem, Xk, Wk, bk, 1.0f, nullptr, k);
  } else {
    gemm_core<64, 128, 2>(smem, Xv, Wv, bv, 1.0f, nullptr, vT);
  }
}

__global__ __launch_bounds__(256, 4) void gemm_o(const unsigned short* __restrict__ A,
                                                 const unsigned short* __restrict__ W,
                                                 const float* __restrict__ bi,
                                                 float* __restrict__ out) {
  __shared__ __align__(16) unsigned short smem[2 * (64 + 64) * 32];  // 16 KB
  gemm_core<64, 64, 1>(smem, A, W, bi, 1.0f, out, nullptr);
}

// ---------------------------------------------------------------------------
// Flash attention, swapped-QK^T, in-register softmax, dbuf K/V staging,
// ones-column MFMA row-sum, defer-max THR=8. Block = (b,h,128 q-rows),
// 4 waves x QBLK=32 q-rows (2 m-frags) -> staging/K-frags amortized 2x.
// ---------------------------------------------------------------------------
__global__ __launch_bounds__(256, 2) void attn_kernel(
    const unsigned short* __restrict__ Qp, const unsigned short* __restrict__ Kp,
    const unsigned short* __restrict__ vTp, unsigned short* __restrict__ Op) {
  __shared__ __align__(16) unsigned short Kt[2][64 * 64];
  __shared__ __align__(16) unsigned short Vt[2][64 * 64];  // [d][s]
  __shared__ __align__(16) unsigned short Pt[4][32 * 64];  // per-wave P (32 rows)
  const int tid = threadIdx.x;
  const int lane = tid & 63, w = tid >> 6;
  const int l15 = lane & 15, l4 = lane >> 4;
  const int bh = blockIdx.x;  // 0..31
  const int b = bh >> 4, h = bh & 15;
  const int qb = blockIdx.y;  // 0..15 (128 rows each)
  const size_t baseQ = (size_t)b * SS * D_MODEL + (size_t)h * DK;
  const size_t baseV = (size_t)(b * 1024 + h * 64) * SS;

  bf16x8 aq[2][2];
#pragma unroll
  for (int m = 0; m < 2; ++m) {
    const int qrow = qb * 128 + w * 32 + m * 16 + l15;
#pragma unroll
    for (int kk = 0; kk < 2; ++kk)
      aq[m][kk] = *(const bf16x8*)&Qp[baseQ + (size_t)qrow * D_MODEL + kk * 32 + l4 * 8];
  }

  const bf16x8 vone = {0x3F80, 0x3F80, 0x3F80, 0x3F80, 0x3F80, 0x3F80, 0x3F80, 0x3F80};

  float rm[2] = {-1e30f, -1e30f};
  f32x4 acc[2][5];  // [m][0..3]=O dims, [m][4]=row-sum
#pragma unroll
  for (int m = 0; m < 2; ++m)
#pragma unroll
    for (int d = 0; d < 5; ++d) acc[m][d] = (f32x4){0.f, 0.f, 0.f, 0.f};

  auto stage = [&](int buf, int kt) {
#pragma unroll
    for (int i = 0; i < 2; ++i) {  // K tile 64x64
      const int flat = (w * 2 + i) * 64 + lane;
      const int row = flat >> 3, g = flat & 7;
      gload16(&Kt[buf][flat * 8],
              &Kp[baseQ + (size_t)(kt * 64 + row) * D_MODEL + ((g ^ (row & 7)) << 3)]);
    }
#pragma unroll
    for (int i = 0; i < 2; ++i) {  // V^T tile: rows d, cols s
      const int flat = (w * 2 + i) * 64 + lane;
      const int row = flat >> 3, g = flat & 7;
      gload16(&Vt[buf][flat * 8],
              &vTp[baseV + (size_t)row * SS + kt * 64 + ((g ^ (row & 7)) << 3)]);
    }
  };

  stage(0, 0);
  __syncthreads();
  int cur = 0;
  for (int kt = 0; kt < SS / 64; ++kt) {
    if (kt + 1 < SS / 64) stage(cur ^ 1, kt + 1);

    // swapped QK^T: st[m][n] reg r = score(q = m*16+l15, key = n*16+l4*4+r)
    f32x4 st[2][4];
#pragma unroll
    for (int m = 0; m < 2; ++m)
#pragma unroll
      for (int n = 0; n < 4; ++n) st[m][n] = (f32x4){0.f, 0.f, 0.f, 0.f};
#pragma unroll
    for (int kk = 0; kk < 2; ++kk) {
      bf16x8 kf[4];
#pragma unroll
      for (int n = 0; n < 4; ++n) {
        const int r = n * 16 + l15;
        kf[n] = *(const bf16x8*)&Kt[cur][r * 64 + (((kk * 4 + l4) ^ (r & 7)) << 3)];
      }
#pragma unroll
      for (int m = 0; m < 2; ++m)
#pragma unroll
        for (int n = 0; n < 4; ++n)
          st[m][n] = __builtin_amdgcn_mfma_f32_16x16x32_bf16(kf[n], aq[m][kk], st[m][n], 0, 0, 0);
    }

    // row max via v_max3 tree + cross-l4 reduce (log2-unit scores)
    float mx[2];
#pragma unroll
    for (int m = 0; m < 2; ++m) {
      const float a0 = max3f(st[m][0][0], st[m][0][1], st[m][0][2]);
      const float a1 = max3f(st[m][0][3], st[m][1][0], st[m][1][1]);
      const float a2 = max3f(st[m][1][2], st[m][1][3], st[m][2][0]);
      const float a3 = max3f(st[m][2][1], st[m][2][2], st[m][2][3]);
      const float a4 = max3f(st[m][3][0], st[m][3][1], st[m][3][2]);
      float v = fmaxf(max3f(a0, a1, a2), max3f(a3, a4, st[m][3][3]));
      v = fmaxf(v, __shfl_xor(v, 16));
      v = fmaxf(v, __shfl_xor(v, 32));
      mx[m] = v;
    }
    if (__any((mx[0] > rm[0] + 8.f) | (mx[1] > rm[1] + 8.f))) {
#pragma unroll
      for (int m = 0; m < 2; ++m) {
        const float nm = fmaxf(rm[m], mx[m]);
        const float alpha = exp2f(rm[m] - nm);
        rm[m] = nm;
#pragma unroll
        for (int r = 0; r < 4; ++r) {
          const float ar = __shfl(alpha, l4 * 4 + r);
#pragma unroll
          for (int d = 0; d < 5; ++d) acc[m][d][r] *= ar;
        }
      }
    }
#pragma unroll
    for (int m = 0; m < 2; ++m)
#pragma unroll
      for (int n = 0; n < 4; ++n)
#pragma unroll
        for (int r = 0; r < 4; ++r) st[m][n][r] = exp2f(st[m][n][r] - rm[m]);

    // P -> per-wave LDS (cvt_pk pairs, swizzled u32 writes; same-wave only)
#pragma unroll
    for (int m = 0; m < 2; ++m)
#pragma unroll
      for (int n = 0; n < 4; ++n)
#pragma unroll
        for (int c = 0; c < 2; ++c) {
          const int col = n * 16 + l4 * 4 + 2 * c;
          const int row = m * 16 + l15;
          const int sw = (((col >> 3) ^ (row & 7)) << 3) + (col & 7);
          *(unsigned*)&Pt[w][row * 64 + sw] = cvtpk(st[m][n][2 * c], st[m][n][2 * c + 1]);
        }

    // PV + ones-column row-sum
#pragma unroll
    for (int kk = 0; kk < 2; ++kk) {
      bf16x8 ap[2], vf[4];
#pragma unroll
      for (int m = 0; m < 2; ++m) {
        const int r = m * 16 + l15;
        ap[m] = *(const bf16x8*)&Pt[w][r * 64 + (((kk * 4 + l4) ^ (r & 7)) << 3)];
      }
#pragma unroll
      for (int d = 0; d < 4; ++d) {
        const int r = d * 16 + l15;
        vf[d] = *(const bf16x8*)&Vt[cur][r * 64 + (((kk * 4 + l4) ^ (r & 7)) << 3)];
      }
#pragma unroll
      for (int m = 0; m < 2; ++m) {
#pragma unroll
        for (int d = 0; d < 4; ++d)
          acc[m][d] = __builtin_amdgcn_mfma_f32_16x16x32_bf16(ap[m], vf[d], acc[m][d], 0, 0, 0);
        acc[m][4] = __builtin_amdgcn_mfma_f32_16x16x32_bf16(ap[m], vone, acc[m][4], 0, 0, 0);
      }
    }

    __syncthreads();
    cur ^= 1;
  }

  // epilogue: rows of acc[m] are q = m*16 + l4*4 + r; acc[m][4][r] = denom
#pragma unroll
  for (int m = 0; m < 2; ++m) {
    float inv[4];
#pragma unroll
    for (int r = 0; r < 4; ++r) inv[r] = 1.0f / acc[m][4][r];
#pragma unroll
    for (int d = 0; d < 4; ++d)
#pragma unroll
      for (int r = 0; r < 4; ++r) {
        const int orow = qb * 128 + w * 32 + m * 16 + l4 * 4 + r;
        Op[baseQ + (size_t)orow * D_MODEL + d * 16 + l15] = f2bf(acc[m][d][r] * inv[r]);
      }
  }
}

extern "C" void kernel_launch(void* const* d_in, const int* in_sizes, int n_in,
                              void* d_out, int out_size, void* d_ws, size_t ws_size,
                              hipStream_t stream) {
  const float* Qin = (const float*)d_in[0];
  const float* Kin = (const float*)d_in[1];
  const float* Vin = (const float*)d_in[2];
  const float* Wq = (const float*)d_in[3];
  const float* bq = (const float*)d_in[4];
  const float* Wk = (const float*)d_in[5];
  const float* bk = (const float*)d_in[6];
  const float* Wv = (const float*)d_in[7];
  const float* bv = (const float*)d_in[8];
  const float* Wo = (const float*)d_in[9];
  const float* bo = (const float*)d_in[10];
  float* out = (float*)d_out;

  const size_t NX = (size_t)MROWS * D_MODEL;
  const size_t NW = (size_t)D_MODEL * D_MODEL;
  unsigned short* ws = (unsigned short*)d_ws;
  unsigned short* q  = ws;            // projected q (bf16, pre-scaled by C1)
  unsigned short* k  = ws + NX;       // projected k
  unsigned short* vT = ws + 2 * NX;   // projected v^T [b*1024+col][s]
  unsigned short* Xq = ws + 3 * NX;   // bf16 inputs (Xq reused as ao)
  unsigned short* Xk = ws + 4 * NX;
  unsigned short* Xv = ws + 5 * NX;
  unsigned short* wq = ws + 6 * NX;
  unsigned short* wk = wq + NW;
  unsigned short* wv = wk + NW;
  unsigned short* wo = wv + NW;
  unsigned short* ao = Xq;

  CvtArgs ca;
  ca.s[0] = Qin; ca.d[0] = Xq; ca.n8[0] = (int)(NX / 8);
  ca.s[1] = Kin; ca.d[1] = Xk; ca.n8[1] = (int)(NX / 8);
  ca.s[2] = Vin; ca.d[2] = Xv; ca.n8[2] = (int)(NX / 8);
  ca.s[3] = Wq;  ca.d[3] = wq; ca.n8[3] = (int)(NW / 8);
  ca.s[4] = Wk;  ca.d[4] = wk; ca.n8[4] = (int)(NW / 8);
  ca.s[5] = Wv;  ca.d[5] = wv; ca.n8[5] = (int)(NW / 8);
  ca.s[6] = Wo;  ca.d[6] = wo; ca.n8[6] = (int)(NW / 8);
  convert_bf16<<<dim3(1024, 7), 256, 0, stream>>>(ca);

  gemm_qkv<<<dim3(D_MODEL / 128, MROWS / 64, 3), 256, 0, stream>>>(
      Xq, Xk, Xv, wq, bq, wk, bk, wv, bv, q, k, vT);
  attn_kernel<<<dim3(BB * NHEAD, SS / 128), 256, 0, stream>>>(q, k, vT, ao);
  gemm_o<<<dim3(D_MODEL / 64, MROWS / 64), 256, 0, stream>>>(ao, wo, bo, out);
}

// Round 6
// 249.896 us; speedup vs baseline: 1.0118x; 1.0118x over previous
//
#include <hip/hip_runtime.h>

// ---------------------------------------------------------------------------
// MHA: out = (softmax(split(XqWq^T+bq) @ split(XkWk^T+bk)^T / 8) @ split(XvWv^T+bv)) @ Wo^T + bo
// B=2, S=2048, D=1024, H=16, Dk=64. fp32 I/O; bf16 MFMA compute.
// R6: GEMMs = m97 clone (128^2 tile, BK=64, single-buffer, 2 barriers, 4 waves
//     x 64x64, MF=NF=4); qkv fused over N=3072; attn = R5 + setprio.
// ---------------------------------------------------------------------------

typedef short bf16x8 __attribute__((ext_vector_type(8)));
typedef float f32x4 __attribute__((ext_vector_type(4)));

#define D_MODEL 1024
#define NHEAD 16
#define DK 64
#define BB 2
#define SS 2048
#define MROWS (BB * SS) /* 4096 */
#define C1 0.18033688011112042f /* (1/8)*log2(e) */

__device__ __forceinline__ unsigned short f2bf(float f) {
  unsigned u = __builtin_bit_cast(unsigned, f);
  u += 0x7fffu + ((u >> 16) & 1u);  // RNE
  return (unsigned short)(u >> 16);
}
__device__ __forceinline__ unsigned pack2(float a, float b) {
  return (unsigned)f2bf(a) | ((unsigned)f2bf(b) << 16);
}
__device__ __forceinline__ unsigned cvtpk(float lo, float hi) {
  unsigned r;
  asm("v_cvt_pk_bf16_f32 %0, %1, %2" : "=v"(r) : "v"(lo), "v"(hi));
  return r;
}
__device__ __forceinline__ float max3f(float a, float b, float c) {
  float d;
  asm("v_max3_f32 %0, %1, %2, %3" : "=v"(d) : "v"(a), "v"(b), "v"(c));
  return d;
}

typedef __attribute__((address_space(3))) unsigned int as3u;
typedef const __attribute__((address_space(1))) unsigned int as1u;
__device__ __forceinline__ void gload16(void* lds, const void* g) {
  __builtin_amdgcn_global_load_lds((as1u*)g, (as3u*)lds, 16, 0, 0);
}

// ---------------------------------------------------------------------------
// fp32 -> bf16 conversion pass
// ---------------------------------------------------------------------------
struct CvtArgs {
  const float* s[7];
  unsigned short* d[7];
  int n8[7];
};

__global__ __launch_bounds__(256) void convert_bf16(CvtArgs a) {
  const int slot = blockIdx.y;
  const float* __restrict__ s = a.s[slot];
  unsigned short* __restrict__ d = a.d[slot];
  const int n8 = a.n8[slot];
  for (int i = blockIdx.x * 256 + threadIdx.x; i < n8; i += gridDim.x * 256) {
    const size_t off = (size_t)i * 8;
    const float4 v0 = *(const float4*)&s[off];
    const float4 v1 = *(const float4*)&s[off + 4];
    uint4 p;
    p.x = pack2(v0.x, v0.y); p.y = pack2(v0.z, v0.w);
    p.z = pack2(v1.x, v1.y); p.w = pack2(v1.z, v1.w);
    *(uint4*)&d[off] = p;
  }
}

// ---------------------------------------------------------------------------
// m97-clone GEMM core: 128x128 tile, BK=64, single-buffer LDS (32 KB),
// 2 barriers/K-step, 4 waves (2x2) x 64x64, MF=NF=4, global_load_lds w=16
// with pre-swizzled source columns. C = A*B^T + bias.
// MODE 0: bf16 C (scaled). MODE 1: f32 C. MODE 2: C^T -> vT[b*1024+col][s].
// For MODE2/qkv: nb = N-tile index within the 1024-col weight.
// ---------------------------------------------------------------------------
template <int MODE>
__device__ __forceinline__ void gemm128(unsigned short* smem,
                                        const unsigned short* __restrict__ A,
                                        const unsigned short* __restrict__ B,
                                        const float* __restrict__ bias,
                                        float scale, int bm, int nb,
                                        float* __restrict__ Cf,
                                        unsigned short* __restrict__ Cb) {
  unsigned short* As = smem;            // [128][64] swizzled content
  unsigned short* Bs = smem + 128 * 64;
  const int tid = threadIdx.x;
  const int lane = tid & 63, w = tid >> 6;
  const int wm = w >> 1, wn = w & 1;
  const int l15 = lane & 15, l4 = lane >> 4;

  f32x4 acc[4][4];
#pragma unroll
  for (int m = 0; m < 4; ++m)
#pragma unroll
    for (int n = 0; n < 4; ++n) acc[m][n] = (f32x4){0.f, 0.f, 0.f, 0.f};

  for (int k0 = 0; k0 < D_MODEL; k0 += 64) {
    __syncthreads();
#pragma unroll
    for (int i = 0; i < 4; ++i) {
      const int flat = i * 256 + tid;
      const int row = flat >> 3, g = flat & 7;
      const int gs = (g ^ (row & 7)) << 3;
      gload16(&As[flat * 8], &A[(size_t)(bm * 128 + row) * D_MODEL + k0 + gs]);
    }
#pragma unroll
    for (int i = 0; i < 4; ++i) {
      const int flat = i * 256 + tid;
      const int row = flat >> 3, g = flat & 7;
      const int gs = (g ^ (row & 7)) << 3;
      gload16(&Bs[flat * 8], &B[(size_t)(nb * 128 + row) * D_MODEL + k0 + gs]);
    }
    __syncthreads();
#pragma unroll
    for (int kk = 0; kk < 2; ++kk) {
      bf16x8 af[4], bf[4];
#pragma unroll
      for (int m = 0; m < 4; ++m) {
        const int r = wm * 64 + m * 16 + l15;
        af[m] = *(const bf16x8*)&As[r * 64 + (((kk * 4 + l4) ^ (r & 7)) << 3)];
      }
#pragma unroll
      for (int n = 0; n < 4; ++n) {
        const int r = wn * 64 + n * 16 + l15;
        bf[n] = *(const bf16x8*)&Bs[r * 64 + (((kk * 4 + l4) ^ (r & 7)) << 3)];
      }
#pragma unroll
      for (int m = 0; m < 4; ++m)
#pragma unroll
        for (int n = 0; n < 4; ++n)
          acc[m][n] = __builtin_amdgcn_mfma_f32_16x16x32_bf16(af[m], bf[n], acc[m][n], 0, 0, 0);
    }
  }

  if (MODE != 2) {
#pragma unroll
    for (int m = 0; m < 4; ++m)
#pragma unroll
      for (int n = 0; n < 4; ++n) {
        const int col = nb * 128 + wn * 64 + n * 16 + l15;
        const float bv = bias[col];
#pragma unroll
        for (int r = 0; r < 4; ++r) {
          const int row = bm * 128 + wm * 64 + m * 16 + l4 * 4 + r;
          const float v = (acc[m][n][r] + bv) * scale;
          if (MODE == 0) Cb[(size_t)row * D_MODEL + col] = f2bf(v);
          else           Cf[(size_t)row * D_MODEL + col] = v;
        }
      }
  } else {
    // C^T through LDS: T[cl][rl], cl in [0,128), pitch 256 B,
    // 16B-group swizzle g = (rl>>3) ^ (cl&7).
    unsigned short* T = smem;  // 32 KB, reuses As+Bs
    __syncthreads();
#pragma unroll
    for (int m = 0; m < 4; ++m)
#pragma unroll
      for (int n = 0; n < 4; ++n) {
        const int cl = wn * 64 + n * 16 + l15;
        const float bv = bias[nb * 128 + cl];
#pragma unroll
        for (int r = 0; r < 4; ++r) {
          const int rl = wm * 64 + m * 16 + l4 * 4 + r;
          const int byte = cl * 256 + ((((rl >> 3) ^ (cl & 7))) << 4) + ((rl & 7) << 1);
          *(unsigned short*)((char*)T + byte) = f2bf(acc[m][n][r] + bv);
        }
      }
    __syncthreads();
#pragma unroll
    for (int c = 0; c < 8; ++c) {
      const int chunk = c * 256 + tid;          // 0..2047
      const int cl = chunk >> 4, rl0 = (chunk & 15) * 8;
      const int byte = cl * 256 + (((rl0 >> 3) ^ (cl & 7)) << 4);
      const uint4 val = *(const uint4*)((const char*)T + byte);
      const int gcol = nb * 128 + cl;
      const int bb = (bm * 128) >> 11;
      const int s = ((bm * 128) & 2047) + rl0;
      *(uint4*)&Cb[(size_t)(bb * 1024 + gcol) * SS + s] = val;
    }
  }
}

// Fused QKV: grid (24, 32). blockIdx.x = 3072-col tile; z = x>>3 picks proj.
__global__ __launch_bounds__(256, 3) void gemm_qkv(
    const unsigned short* __restrict__ Xq, const unsigned short* __restrict__ Xk,
    const unsigned short* __restrict__ Xv,
    const unsigned short* __restrict__ Wq, const float* __restrict__ bq,
    const unsigned short* __restrict__ Wk, const float* __restrict__ bk,
    const unsigned short* __restrict__ Wv, const float* __restrict__ bv,
    unsigned short* __restrict__ q, unsigned short* __restrict__ k,
    unsigned short* __restrict__ vT) {
  __shared__ __align__(16) unsigned short smem[2 * 128 * 64];  // 32 KB
  const int bn = blockIdx.x, bm = blockIdx.y;
  const int z = bn >> 3, nb = bn & 7;
  if (z == 0) {
    gemm128<0>(smem, Xq, Wq, bq, C1, bm, nb, nullptr, q);  // q pre-scaled
  } else if (z == 1) {
    gemm128<0>(smem, Xk, Wk, bk, 1.0f, bm, nb, nullptr, k);
  } else {
    gemm128<2>(smem, Xv, Wv, bv, 1.0f, bm, nb, nullptr, vT);
  }
}

__global__ __launch_bounds__(256, 3) void gemm_o(const unsigned short* __restrict__ A,
                                                 const unsigned short* __restrict__ W,
                                                 const float* __restrict__ bi,
                                                 float* __restrict__ out) {
  __shared__ __align__(16) unsigned short smem[2 * 128 * 64];  // 32 KB
  gemm128<1>(smem, A, W, bi, 1.0f, blockIdx.y, blockIdx.x, out, nullptr);
}

// ---------------------------------------------------------------------------
// Flash attention, swapped-QK^T, in-register softmax, dbuf K/V staging,
// ones-column MFMA row-sum, defer-max THR=8, setprio around MFMA clusters.
// Block = (b,h,128 q-rows), 4 waves x QBLK=32 q-rows.
// ---------------------------------------------------------------------------
__global__ __launch_bounds__(256, 2) void attn_kernel(
    const unsigned short* __restrict__ Qp, const unsigned short* __restrict__ Kp,
    const unsigned short* __restrict__ vTp, unsigned short* __restrict__ Op) {
  __shared__ __align__(16) unsigned short Kt[2][64 * 64];
  __shared__ __align__(16) unsigned short Vt[2][64 * 64];  // [d][s]
  __shared__ __align__(16) unsigned short Pt[4][32 * 64];  // per-wave P (32 rows)
  const int tid = threadIdx.x;
  const int lane = tid & 63, w = tid >> 6;
  const int l15 = lane & 15, l4 = lane >> 4;
  const int bh = blockIdx.x;  // 0..31
  const int b = bh >> 4, h = bh & 15;
  const int qb = blockIdx.y;  // 0..15 (128 rows each)
  const size_t baseQ = (size_t)b * SS * D_MODEL + (size_t)h * DK;
  const size_t baseV = (size_t)(b * 1024 + h * 64) * SS;

  bf16x8 aq[2][2];
#pragma unroll
  for (int m = 0; m < 2; ++m) {
    const int qrow = qb * 128 + w * 32 + m * 16 + l15;
#pragma unroll
    for (int kk = 0; kk < 2; ++kk)
      aq[m][kk] = *(const bf16x8*)&Qp[baseQ + (size_t)qrow * D_MODEL + kk * 32 + l4 * 8];
  }

  const bf16x8 vone = {0x3F80, 0x3F80, 0x3F80, 0x3F80, 0x3F80, 0x3F80, 0x3F80, 0x3F80};

  float rm[2] = {-1e30f, -1e30f};
  f32x4 acc[2][5];  // [m][0..3]=O dims, [m][4]=row-sum
#pragma unroll
  for (int m = 0; m < 2; ++m)
#pragma unroll
    for (int d = 0; d < 5; ++d) acc[m][d] = (f32x4){0.f, 0.f, 0.f, 0.f};

  auto stage = [&](int buf, int kt) {
#pragma unroll
    for (int i = 0; i < 2; ++i) {  // K tile 64x64
      const int flat = (w * 2 + i) * 64 + lane;
      const int row = flat >> 3, g = flat & 7;
      gload16(&Kt[buf][flat * 8],
              &Kp[baseQ + (size_t)(kt * 64 + row) * D_MODEL + ((g ^ (row & 7)) << 3)]);
    }
#pragma unroll
    for (int i = 0; i < 2; ++i) {  // V^T tile: rows d, cols s
      const int flat = (w * 2 + i) * 64 + lane;
      const int row = flat >> 3, g = flat & 7;
      gload16(&Vt[buf][flat * 8],
              &vTp[baseV + (size_t)row * SS + kt * 64 + ((g ^ (row & 7)) << 3)]);
    }
  };

  stage(0, 0);
  __syncthreads();
  int cur = 0;
  for (int kt = 0; kt < SS / 64; ++kt) {
    if (kt + 1 < SS / 64) stage(cur ^ 1, kt + 1);

    // swapped QK^T: st[m][n] reg r = score(q = m*16+l15, key = n*16+l4*4+r)
    f32x4 st[2][4];
#pragma unroll
    for (int m = 0; m < 2; ++m)
#pragma unroll
      for (int n = 0; n < 4; ++n) st[m][n] = (f32x4){0.f, 0.f, 0.f, 0.f};
#pragma unroll
    for (int kk = 0; kk < 2; ++kk) {
      bf16x8 kf[4];
#pragma unroll
      for (int n = 0; n < 4; ++n) {
        const int r = n * 16 + l15;
        kf[n] = *(const bf16x8*)&Kt[cur][r * 64 + (((kk * 4 + l4) ^ (r & 7)) << 3)];
      }
      __builtin_amdgcn_s_setprio(1);
#pragma unroll
      for (int m = 0; m < 2; ++m)
#pragma unroll
        for (int n = 0; n < 4; ++n)
          st[m][n] = __builtin_amdgcn_mfma_f32_16x16x32_bf16(kf[n], aq[m][kk], st[m][n], 0, 0, 0);
      __builtin_amdgcn_s_setprio(0);
    }

    // row max via v_max3 tree + cross-l4 reduce (log2-unit scores)
    float mx[2];
#pragma unroll
    for (int m = 0; m < 2; ++m) {
      const float a0 = max3f(st[m][0][0], st[m][0][1], st[m][0][2]);
      const float a1 = max3f(st[m][0][3], st[m][1][0], st[m][1][1]);
      const float a2 = max3f(st[m][1][2], st[m][1][3], st[m][2][0]);
      const float a3 = max3f(st[m][2][1], st[m][2][2], st[m][2][3]);
      const float a4 = max3f(st[m][3][0], st[m][3][1], st[m][3][2]);
      float v = fmaxf(max3f(a0, a1, a2), max3f(a3, a4, st[m][3][3]));
      v = fmaxf(v, __shfl_xor(v, 16));
      v = fmaxf(v, __shfl_xor(v, 32));
      mx[m] = v;
    }
    if (__any((mx[0] > rm[0] + 8.f) | (mx[1] > rm[1] + 8.f))) {
#pragma unroll
      for (int m = 0; m < 2; ++m) {
        const float nm = fmaxf(rm[m], mx[m]);
        const float alpha = exp2f(rm[m] - nm);
        rm[m] = nm;
#pragma unroll
        for (int r = 0; r < 4; ++r) {
          const float ar = __shfl(alpha, l4 * 4 + r);
#pragma unroll
          for (int d = 0; d < 5; ++d) acc[m][d][r] *= ar;
        }
      }
    }
#pragma unroll
    for (int m = 0; m < 2; ++m)
#pragma unroll
      for (int n = 0; n < 4; ++n)
#pragma unroll
        for (int r = 0; r < 4; ++r) st[m][n][r] = exp2f(st[m][n][r] - rm[m]);

    // P -> per-wave LDS (cvt_pk pairs, swizzled u32 writes; same-wave only)
#pragma unroll
    for (int m = 0; m < 2; ++m)
#pragma unroll
      for (int n = 0; n < 4; ++n)
#pragma unroll
        for (int c = 0; c < 2; ++c) {
          const int col = n * 16 + l4 * 4 + 2 * c;
          const int row = m * 16 + l15;
          const int sw = (((col >> 3) ^ (row & 7)) << 3) + (col & 7);
          *(unsigned*)&Pt[w][row * 64 + sw] = cvtpk(st[m][n][2 * c], st[m][n][2 * c + 1]);
        }

    // PV + ones-column row-sum
#pragma unroll
    for (int kk = 0; kk < 2; ++kk) {
      bf16x8 ap[2], vf[4];
#pragma unroll
      for (int m = 0; m < 2; ++m) {
        const int r = m * 16 + l15;
        ap[m] = *(const bf16x8*)&Pt[w][r * 64 + (((kk * 4 + l4) ^ (r & 7)) << 3)];
      }
#pragma unroll
      for (int d = 0; d < 4; ++d) {
        const int r = d * 16 + l15;
        vf[d] = *(const bf16x8*)&Vt[cur][r * 64 + (((kk * 4 + l4) ^ (r & 7)) << 3)];
      }
      __builtin_amdgcn_s_setprio(1);
#pragma unroll
      for (int m = 0; m < 2; ++m) {
#pragma unroll
        for (int d = 0; d < 4; ++d)
          acc[m][d] = __builtin_amdgcn_mfma_f32_16x16x32_bf16(ap[m], vf[d], acc[m][d], 0, 0, 0);
        acc[m][4] = __builtin_amdgcn_mfma_f32_16x16x32_bf16(ap[m], vone, acc[m][4], 0, 0, 0);
      }
      __builtin_amdgcn_s_setprio(0);
    }

    __syncthreads();
    cur ^= 1;
  }

  // epilogue: rows of acc[m] are q = m*16 + l4*4 + r; acc[m][4][r] = denom
#pragma unroll
  for (int m = 0; m < 2; ++m) {
    float inv[4];
#pragma unroll
    for (int r = 0; r < 4; ++r) inv[r] = 1.0f / acc[m][4][r];
#pragma unroll
    for (int d = 0; d < 4; ++d)
#pragma unroll
      for (int r = 0; r < 4; ++r) {
        const int orow = qb * 128 + w * 32 + m * 16 + l4 * 4 + r;
        Op[baseQ + (size_t)orow * D_MODEL + d * 16 + l15] = f2bf(acc[m][d][r] * inv[r]);
      }
  }
}

extern "C" void kernel_launch(void* const* d_in, const int* in_sizes, int n_in,
                              void* d_out, int out_size, void* d_ws, size_t ws_size,
                              hipStream_t stream) {
  const float* Qin = (const float*)d_in[0];
  const float* Kin = (const float*)d_in[1];
  const float* Vin = (const float*)d_in[2];
  const float* Wq = (const float*)d_in[3];
  const float* bq = (const float*)d_in[4];
  const float* Wk = (const float*)d_in[5];
  const float* bk = (const float*)d_in[6];
  const float* Wv = (const float*)d_in[7];
  const float* bv = (const float*)d_in[8];
  const float* Wo = (const float*)d_in[9];
  const float* bo = (const float*)d_in[10];
  float* out = (float*)d_out;

  const size_t NX = (size_t)MROWS * D_MODEL;
  const size_t NW = (size_t)D_MODEL * D_MODEL;
  unsigned short* ws = (unsigned short*)d_ws;
  unsigned short* q  = ws;            // projected q (bf16, pre-scaled by C1)
  unsigned short* k  = ws + NX;       // projected k
  unsigned short* vT = ws + 2 * NX;   // projected v^T [b*1024+col][s]
  unsigned short* Xq = ws + 3 * NX;   // bf16 inputs (Xq reused as ao)
  unsigned short* Xk = ws + 4 * NX;
  unsigned short* Xv = ws + 5 * NX;
  unsigned short* wq = ws + 6 * NX;
  unsigned short* wk = wq + NW;
  unsigned short* wv = wk + NW;
  unsigned short* wo = wv + NW;
  unsigned short* ao = Xq;

  CvtArgs ca;
  ca.s[0] = Qin; ca.d[0] = Xq; ca.n8[0] = (int)(NX / 8);
  ca.s[1] = Kin; ca.d[1] = Xk; ca.n8[1] = (int)(NX / 8);
  ca.s[2] = Vin; ca.d[2] = Xv; ca.n8[2] = (int)(NX / 8);
  ca.s[3] = Wq;  ca.d[3] = wq; ca.n8[3] = (int)(NW / 8);
  ca.s[4] = Wk;  ca.d[4] = wk; ca.n8[4] = (int)(NW / 8);
  ca.s[5] = Wv;  ca.d[5] = wv; ca.n8[5] = (int)(NW / 8);
  ca.s[6] = Wo;  ca.d[6] = wo; ca.n8[6] = (int)(NW / 8);
  convert_bf16<<<dim3(1024, 7), 256, 0, stream>>>(ca);

  gemm_qkv<<<dim3(24, 32), 256, 0, stream>>>(
      Xq, Xk, Xv, wq, bq, wk, bk, wv, bv, q, k, vT);
  attn_kernel<<<dim3(BB * NHEAD, SS / 128), 256, 0, stream>>>(q, k, vT, ao);
  gemm_o<<<dim3(8, 32), 256, 0, stream>>>(ao, wo, bo, out);
}

// Round 7
// 237.337 us; speedup vs baseline: 1.0653x; 1.0529x over previous
//
#include <hip/hip_runtime.h>

// ---------------------------------------------------------------------------
// MHA: out = (softmax(split(XqWq^T+bq) @ split(XkWk^T+bk)^T / 8) @ split(XvWv^T+bv)) @ Wo^T + bo
// B=2, S=2048, D=1024, H=16, Dk=64. fp32 I/O; bf16 MFMA compute.
// R7: counted-vmcnt 3-buffer-ring pipelines (2-deep prefetch, raw barriers,
//     never drain vmcnt to 0 mid-loop) for GEMMs and attention staging.
//     XCD-chunked block swizzle on GEMM grids. setprio removed (R6 regression).
// ---------------------------------------------------------------------------

typedef short bf16x8 __attribute__((ext_vector_type(8)));
typedef float f32x4 __attribute__((ext_vector_type(4)));

#define D_MODEL 1024
#define NHEAD 16
#define DK 64
#define BB 2
#define SS 2048
#define MROWS (BB * SS) /* 4096 */
#define C1 0.18033688011112042f /* (1/8)*log2(e) */

__device__ __forceinline__ unsigned short f2bf(float f) {
  unsigned u = __builtin_bit_cast(unsigned, f);
  u += 0x7fffu + ((u >> 16) & 1u);  // RNE
  return (unsigned short)(u >> 16);
}
__device__ __forceinline__ unsigned pack2(float a, float b) {
  return (unsigned)f2bf(a) | ((unsigned)f2bf(b) << 16);
}
__device__ __forceinline__ unsigned cvtpk(float lo, float hi) {
  unsigned r;
  asm("v_cvt_pk_bf16_f32 %0, %1, %2" : "=v"(r) : "v"(lo), "v"(hi));
  return r;
}
__device__ __forceinline__ float max3f(float a, float b, float c) {
  float d;
  asm("v_max3_f32 %0, %1, %2, %3" : "=v"(d) : "v"(a), "v"(b), "v"(c));
  return d;
}

typedef __attribute__((address_space(3))) unsigned int as3u;
typedef const __attribute__((address_space(1))) unsigned int as1u;
__device__ __forceinline__ void gload16(void* lds, const void* g) {
  __builtin_amdgcn_global_load_lds((as1u*)g, (as3u*)lds, 16, 0, 0);
}
// Counted waits: loads stay in flight across barriers (T4).
__device__ __forceinline__ void waitv16() { asm volatile("s_waitcnt vmcnt(16)" ::: "memory"); }
__device__ __forceinline__ void waitv8()  { asm volatile("s_waitcnt vmcnt(8)"  ::: "memory"); }
__device__ __forceinline__ void waitv4()  { asm volatile("s_waitcnt vmcnt(4)"  ::: "memory"); }
__device__ __forceinline__ void waitv0()  { asm volatile("s_waitcnt vmcnt(0)"  ::: "memory"); }

// ---------------------------------------------------------------------------
// fp32 -> bf16 conversion pass
// ---------------------------------------------------------------------------
struct CvtArgs {
  const float* s[7];
  unsigned short* d[7];
  int n8[7];
};

__global__ __launch_bounds__(256) void convert_bf16(CvtArgs a) {
  const int slot = blockIdx.y;
  const float* __restrict__ s = a.s[slot];
  unsigned short* __restrict__ d = a.d[slot];
  const int n8 = a.n8[slot];
  for (int i = blockIdx.x * 256 + threadIdx.x; i < n8; i += gridDim.x * 256) {
    const size_t off = (size_t)i * 8;
    const float4 v0 = *(const float4*)&s[off];
    const float4 v1 = *(const float4*)&s[off + 4];
    uint4 p;
    p.x = pack2(v0.x, v0.y); p.y = pack2(v0.z, v0.w);
    p.z = pack2(v1.x, v1.y); p.w = pack2(v1.z, v1.w);
    *(uint4*)&d[off] = p;
  }
}

// ---------------------------------------------------------------------------
// GEMM core: 128x128 tile, BK=64, 3-buffer ring (96 KB LDS), 2-deep prefetch,
// counted vmcnt, raw barriers. 4 waves (2x2) x 64x64. C = A*B^T + bias.
// MODE 0: bf16 C (scaled). MODE 1: f32 C. MODE 2: C^T -> vT[b*1024+col][s].
// ---------------------------------------------------------------------------
template <int MODE>
__device__ __forceinline__ void gemm128(unsigned short* smem,
                                        const unsigned short* __restrict__ A,
                                        const unsigned short* __restrict__ B,
                                        const float* __restrict__ bias,
                                        float scale, int bm, int nb,
                                        float* __restrict__ Cf,
                                        unsigned short* __restrict__ Cb) {
  const int BUF = 2 * 128 * 64;  // elements per ring slot (A half + B half)
  const int tid = threadIdx.x;
  const int lane = tid & 63, w = tid >> 6;
  const int wm = w >> 1, wn = w & 1;
  const int l15 = lane & 15, l4 = lane >> 4;

  auto stage = [&](int slot, int k0) {  // 8 gload instructions per thread
    unsigned short* As = smem + slot * BUF;
    unsigned short* Bs = As + 128 * 64;
#pragma unroll
    for (int i = 0; i < 4; ++i) {
      const int flat = i * 256 + tid;
      const int row = flat >> 3, g = flat & 7;
      const int gs = (g ^ (row & 7)) << 3;
      gload16(&As[flat * 8], &A[(size_t)(bm * 128 + row) * D_MODEL + k0 + gs]);
    }
#pragma unroll
    for (int i = 0; i < 4; ++i) {
      const int flat = i * 256 + tid;
      const int row = flat >> 3, g = flat & 7;
      const int gs = (g ^ (row & 7)) << 3;
      gload16(&Bs[flat * 8], &B[(size_t)(nb * 128 + row) * D_MODEL + k0 + gs]);
    }
  };

  f32x4 acc[4][4];
#pragma unroll
  for (int m = 0; m < 4; ++m)
#pragma unroll
    for (int n = 0; n < 4; ++n) acc[m][n] = (f32x4){0.f, 0.f, 0.f, 0.f};

  stage(0, 0);
  stage(1, 64);
#pragma unroll
  for (int t = 0; t < 16; ++t) {
    if (t + 2 < 16) stage((t + 2) % 3, (t + 2) * 64);
    // need tile t's 8 loads complete; up to 16 newer stay in flight
    if (t < 14) waitv16();
    else if (t == 14) waitv8();
    else waitv0();
    __builtin_amdgcn_s_barrier();
    unsigned short* As = smem + (t % 3) * BUF;
    unsigned short* Bs = As + 128 * 64;
#pragma unroll
    for (int kk = 0; kk < 2; ++kk) {
      bf16x8 af[4], bf[4];
#pragma unroll
      for (int m = 0; m < 4; ++m) {
        const int r = wm * 64 + m * 16 + l15;
        af[m] = *(const bf16x8*)&As[r * 64 + (((kk * 4 + l4) ^ (r & 7)) << 3)];
      }
#pragma unroll
      for (int n = 0; n < 4; ++n) {
        const int r = wn * 64 + n * 16 + l15;
        bf[n] = *(const bf16x8*)&Bs[r * 64 + (((kk * 4 + l4) ^ (r & 7)) << 3)];
      }
#pragma unroll
      for (int m = 0; m < 4; ++m)
#pragma unroll
        for (int n = 0; n < 4; ++n)
          acc[m][n] = __builtin_amdgcn_mfma_f32_16x16x32_bf16(af[m], bf[n], acc[m][n], 0, 0, 0);
    }
    __builtin_amdgcn_s_barrier();  // protects ring slot reuse by next stage
  }

  if (MODE != 2) {
#pragma unroll
    for (int m = 0; m < 4; ++m)
#pragma unroll
      for (int n = 0; n < 4; ++n) {
        const int col = nb * 128 + wn * 64 + n * 16 + l15;
        const float bv = bias[col];
#pragma unroll
        for (int r = 0; r < 4; ++r) {
          const int row = bm * 128 + wm * 64 + m * 16 + l4 * 4 + r;
          const float v = (acc[m][n][r] + bv) * scale;
          if (MODE == 0) Cb[(size_t)row * D_MODEL + col] = f2bf(v);
          else           Cf[(size_t)row * D_MODEL + col] = v;
        }
      }
  } else {
    // C^T through LDS: T[cl][rl], pitch 256 B, group swizzle (rl>>3)^(cl&7)
    unsigned short* T = smem;
#pragma unroll
    for (int m = 0; m < 4; ++m)
#pragma unroll
      for (int n = 0; n < 4; ++n) {
        const int cl = wn * 64 + n * 16 + l15;
        const float bv = bias[nb * 128 + cl];
#pragma unroll
        for (int r = 0; r < 4; ++r) {
          const int rl = wm * 64 + m * 16 + l4 * 4 + r;
          const int byte = cl * 256 + ((((rl >> 3) ^ (cl & 7))) << 4) + ((rl & 7) << 1);
          *(unsigned short*)((char*)T + byte) = f2bf(acc[m][n][r] + bv);
        }
      }
    __syncthreads();
#pragma unroll
    for (int c = 0; c < 8; ++c) {
      const int chunk = c * 256 + tid;  // 0..2047
      const int cl = chunk >> 4, rl0 = (chunk & 15) * 8;
      const int byte = cl * 256 + (((rl0 >> 3) ^ (cl & 7)) << 4);
      const uint4 val = *(const uint4*)((const char*)T + byte);
      const int gcol = nb * 128 + cl;
      const int bb = (bm * 128) >> 11;
      const int s = ((bm * 128) & 2047) + rl0;
      *(uint4*)&Cb[(size_t)(bb * 1024 + gcol) * SS + s] = val;
    }
  }
}

// Fused QKV: 768 blocks, XCD-chunked swizzle (768 % 8 == 0 -> bijective).
__global__ __launch_bounds__(256, 1) void gemm_qkv(
    const unsigned short* __restrict__ Xq, const unsigned short* __restrict__ Xk,
    const unsigned short* __restrict__ Xv,
    const unsigned short* __restrict__ Wq, const float* __restrict__ bq,
    const unsigned short* __restrict__ Wk, const float* __restrict__ bk,
    const unsigned short* __restrict__ Wv, const float* __restrict__ bv,
    unsigned short* __restrict__ q, unsigned short* __restrict__ k,
    unsigned short* __restrict__ vT) {
  __shared__ __align__(16) unsigned short smem[3 * 2 * 128 * 64];  // 96 KB
  const int lin = blockIdx.x + 24 * blockIdx.y;        // 0..767
  const int swz = (lin % 8) * 96 + lin / 8;            // contiguous per XCD
  const int bn = swz % 24, bm = swz / 24;
  const int z = bn >> 3, nb = bn & 7;
  if (z < 2) {
    const unsigned short* X = z ? Xk : Xq;
    const unsigned short* W = z ? Wk : Wq;
    const float* bi = z ? bk : bq;
    unsigned short* O = z ? k : q;
    gemm128<0>(smem, X, W, bi, z ? 1.0f : C1, bm, nb, nullptr, O);
  } else {
    gemm128<2>(smem, Xv, Wv, bv, 1.0f, bm, nb, nullptr, vT);
  }
}

__global__ __launch_bounds__(256, 1) void gemm_o(const unsigned short* __restrict__ A,
                                                 const unsigned short* __restrict__ W,
                                                 const float* __restrict__ bi,
                                                 float* __restrict__ out) {
  __shared__ __align__(16) unsigned short smem[3 * 2 * 128 * 64];  // 96 KB
  const int lin = blockIdx.x + 8 * blockIdx.y;         // 0..255
  const int swz = (lin % 8) * 32 + lin / 8;
  const int bn = swz % 8, bm = swz / 8;
  gemm128<1>(smem, A, W, bi, 1.0f, bm, bn, out, nullptr);
}

// ---------------------------------------------------------------------------
// Flash attention, swapped-QK^T, in-register softmax, 3-ring K/V staging with
// counted vmcnt (2-deep), ones-column MFMA row-sum, defer-max THR=8.
// Block = (b,h,128 q-rows), 4 waves x QBLK=32 q-rows. LDS 64 KB.
// ---------------------------------------------------------------------------
__global__ __launch_bounds__(256, 2) void attn_kernel(
    const unsigned short* __restrict__ Qp, const unsigned short* __restrict__ Kp,
    const unsigned short* __restrict__ vTp, unsigned short* __restrict__ Op) {
  __shared__ __align__(16) unsigned short Kt[3][64 * 64];
  __shared__ __align__(16) unsigned short Vt[3][64 * 64];  // [d][s]
  __shared__ __align__(16) unsigned short Pt[4][32 * 64];  // per-wave P
  const int tid = threadIdx.x;
  const int lane = tid & 63, w = tid >> 6;
  const int l15 = lane & 15, l4 = lane >> 4;
  const int bh = blockIdx.x;  // 0..31
  const int b = bh >> 4, h = bh & 15;
  const int qb = blockIdx.y;  // 0..15
  const size_t baseQ = (size_t)b * SS * D_MODEL + (size_t)h * DK;
  const size_t baseV = (size_t)(b * 1024 + h * 64) * SS;

  bf16x8 aq[2][2];
#pragma unroll
  for (int m = 0; m < 2; ++m) {
    const int qrow = qb * 128 + w * 32 + m * 16 + l15;
#pragma unroll
    for (int kk = 0; kk < 2; ++kk)
      aq[m][kk] = *(const bf16x8*)&Qp[baseQ + (size_t)qrow * D_MODEL + kk * 32 + l4 * 8];
  }

  const bf16x8 vone = {0x3F80, 0x3F80, 0x3F80, 0x3F80, 0x3F80, 0x3F80, 0x3F80, 0x3F80};

  float rm[2] = {-1e30f, -1e30f};
  f32x4 acc[2][5];  // [m][0..3]=O dims, [m][4]=row-sum
#pragma unroll
  for (int m = 0; m < 2; ++m)
#pragma unroll
    for (int d = 0; d < 5; ++d) acc[m][d] = (f32x4){0.f, 0.f, 0.f, 0.f};

  auto stage = [&](int buf, int kt) {  // 4 gload instructions per thread
#pragma unroll
    for (int i = 0; i < 2; ++i) {  // K tile 64x64
      const int flat = (w * 2 + i) * 64 + lane;
      const int row = flat >> 3, g = flat & 7;
      gload16(&Kt[buf][flat * 8],
              &Kp[baseQ + (size_t)(kt * 64 + row) * D_MODEL + ((g ^ (row & 7)) << 3)]);
    }
#pragma unroll
    for (int i = 0; i < 2; ++i) {  // V^T tile: rows d, cols s
      const int flat = (w * 2 + i) * 64 + lane;
      const int row = flat >> 3, g = flat & 7;
      gload16(&Vt[buf][flat * 8],
              &vTp[baseV + (size_t)row * SS + kt * 64 + ((g ^ (row & 7)) << 3)]);
    }
  };

  stage(0, 0);
  stage(1, 1);
#pragma unroll 1
  for (int kt = 0; kt < SS / 64; ++kt) {
    const int bs = kt % 3;
    if (kt < SS / 64 - 2) {
      int bst = bs + 2; if (bst >= 3) bst -= 3;
      stage(bst, kt + 2);
    }
    if (kt < SS / 64 - 2) waitv8();
    else if (kt == SS / 64 - 2) waitv4();
    else waitv0();
    __builtin_amdgcn_s_barrier();

    // swapped QK^T: st[m][n] reg r = score(q = m*16+l15, key = n*16+l4*4+r)
    f32x4 st[2][4];
#pragma unroll
    for (int m = 0; m < 2; ++m)
#pragma unroll
      for (int n = 0; n < 4; ++n) st[m][n] = (f32x4){0.f, 0.f, 0.f, 0.f};
#pragma unroll
    for (int kk = 0; kk < 2; ++kk) {
      bf16x8 kf[4];
#pragma unroll
      for (int n = 0; n < 4; ++n) {
        const int r = n * 16 + l15;
        kf[n] = *(const bf16x8*)&Kt[bs][r * 64 + (((kk * 4 + l4) ^ (r & 7)) << 3)];
      }
#pragma unroll
      for (int m = 0; m < 2; ++m)
#pragma unroll
        for (int n = 0; n < 4; ++n)
          st[m][n] = __builtin_amdgcn_mfma_f32_16x16x32_bf16(kf[n], aq[m][kk], st[m][n], 0, 0, 0);
    }

    // row max via v_max3 tree + cross-l4 reduce (log2-unit scores)
    float mx[2];
#pragma unroll
    for (int m = 0; m < 2; ++m) {
      const float a0 = max3f(st[m][0][0], st[m][0][1], st[m][0][2]);
      const float a1 = max3f(st[m][0][3], st[m][1][0], st[m][1][1]);
      const float a2 = max3f(st[m][1][2], st[m][1][3], st[m][2][0]);
      const float a3 = max3f(st[m][2][1], st[m][2][2], st[m][2][3]);
      const float a4 = max3f(st[m][3][0], st[m][3][1], st[m][3][2]);
      float v = fmaxf(max3f(a0, a1, a2), max3f(a3, a4, st[m][3][3]));
      v = fmaxf(v, __shfl_xor(v, 16));
      v = fmaxf(v, __shfl_xor(v, 32));
      mx[m] = v;
    }
    if (__any((mx[0] > rm[0] + 8.f) | (mx[1] > rm[1] + 8.f))) {
#pragma unroll
      for (int m = 0; m < 2; ++m) {
        const float nm = fmaxf(rm[m], mx[m]);
        const float alpha = exp2f(rm[m] - nm);
        rm[m] = nm;
#pragma unroll
        for (int r = 0; r < 4; ++r) {
          const float ar = __shfl(alpha, l4 * 4 + r);
#pragma unroll
          for (int d = 0; d < 5; ++d) acc[m][d][r] *= ar;
        }
      }
    }
#pragma unroll
    for (int m = 0; m < 2; ++m)
#pragma unroll
      for (int n = 0; n < 4; ++n)
#pragma unroll
        for (int r = 0; r < 4; ++r) st[m][n][r] = exp2f(st[m][n][r] - rm[m]);

    // P -> per-wave LDS (cvt_pk pairs, swizzled u32 writes; same-wave only)
#pragma unroll
    for (int m = 0; m < 2; ++m)
#pragma unroll
      for (int n = 0; n < 4; ++n)
#pragma unroll
        for (int c = 0; c < 2; ++c) {
          const int col = n * 16 + l4 * 4 + 2 * c;
          const int row = m * 16 + l15;
          const int sw = (((col >> 3) ^ (row & 7)) << 3) + (col & 7);
          *(unsigned*)&Pt[w][row * 64 + sw] = cvtpk(st[m][n][2 * c], st[m][n][2 * c + 1]);
        }

    // PV + ones-column row-sum
#pragma unroll
    for (int kk = 0; kk < 2; ++kk) {
      bf16x8 ap[2], vf[4];
#pragma unroll
      for (int m = 0; m < 2; ++m) {
        const int r = m * 16 + l15;
        ap[m] = *(const bf16x8*)&Pt[w][r * 64 + (((kk * 4 + l4) ^ (r & 7)) << 3)];
      }
#pragma unroll
      for (int d = 0; d < 4; ++d) {
        const int r = d * 16 + l15;
        vf[d] = *(const bf16x8*)&Vt[bs][r * 64 + (((kk * 4 + l4) ^ (r & 7)) << 3)];
      }
#pragma unroll
      for (int m = 0; m < 2; ++m) {
#pragma unroll
        for (int d = 0; d < 4; ++d)
          acc[m][d] = __builtin_amdgcn_mfma_f32_16x16x32_bf16(ap[m], vf[d], acc[m][d], 0, 0, 0);
        acc[m][4] = __builtin_amdgcn_mfma_f32_16x16x32_bf16(ap[m], vone, acc[m][4], 0, 0, 0);
      }
    }

    __builtin_amdgcn_s_barrier();  // protects ring slot reuse by next stage
  }

  // epilogue: rows of acc[m] are q = m*16 + l4*4 + r; acc[m][4][r] = denom
#pragma unroll
  for (int m = 0; m < 2; ++m) {
    float inv[4];
#pragma unroll
    for (int r = 0; r < 4; ++r) inv[r] = 1.0f / acc[m][4][r];
#pragma unroll
    for (int d = 0; d < 4; ++d)
#pragma unroll
      for (int r = 0; r < 4; ++r) {
        const int orow = qb * 128 + w * 32 + m * 16 + l4 * 4 + r;
        Op[baseQ + (size_t)orow * D_MODEL + d * 16 + l15] = f2bf(acc[m][d][r] * inv[r]);
      }
  }
}

extern "C" void kernel_launch(void* const* d_in, const int* in_sizes, int n_in,
                              void* d_out, int out_size, void* d_ws, size_t ws_size,
                              hipStream_t stream) {
  const float* Qin = (const float*)d_in[0];
  const float* Kin = (const float*)d_in[1];
  const float* Vin = (const float*)d_in[2];
  const float* Wq = (const float*)d_in[3];
  const float* bq = (const float*)d_in[4];
  const float* Wk = (const float*)d_in[5];
  const float* bk = (const float*)d_in[6];
  const float* Wv = (const float*)d_in[7];
  const float* bv = (const float*)d_in[8];
  const float* Wo = (const float*)d_in[9];
  const float* bo = (const float*)d_in[10];
  float* out = (float*)d_out;

  const size_t NX = (size_t)MROWS * D_MODEL;
  const size_t NW = (size_t)D_MODEL * D_MODEL;
  unsigned short* ws = (unsigned short*)d_ws;
  unsigned short* q  = ws;            // projected q (bf16, pre-scaled by C1)
  unsigned short* k  = ws + NX;       // projected k
  unsigned short* vT = ws + 2 * NX;   // projected v^T [b*1024+col][s]
  unsigned short* Xq = ws + 3 * NX;   // bf16 inputs (Xq reused as ao)
  unsigned short* Xk = ws + 4 * NX;
  unsigned short* Xv = ws + 5 * NX;
  unsigned short* wq = ws + 6 * NX;
  unsigned short* wk = wq + NW;
  unsigned short* wv = wk + NW;
  unsigned short* wo = wv + NW;
  unsigned short* ao = Xq;

  CvtArgs ca;
  ca.s[0] = Qin; ca.d[0] = Xq; ca.n8[0] = (int)(NX / 8);
  ca.s[1] = Kin; ca.d[1] = Xk; ca.n8[1] = (int)(NX / 8);
  ca.s[2] = Vin; ca.d[2] = Xv; ca.n8[2] = (int)(NX / 8);
  ca.s[3] = Wq;  ca.d[3] = wq; ca.n8[3] = (int)(NW / 8);
  ca.s[4] = Wk;  ca.d[4] = wk; ca.n8[4] = (int)(NW / 8);
  ca.s[5] = Wv;  ca.d[5] = wv; ca.n8[5] = (int)(NW / 8);
  ca.s[6] = Wo;  ca.d[6] = wo; ca.n8[6] = (int)(NW / 8);
  convert_bf16<<<dim3(1024, 7), 256, 0, stream>>>(ca);

  gemm_qkv<<<dim3(24, 32), 256, 0, stream>>>(
      Xq, Xk, Xv, wq, bq, wk, bk, wv, bv, q, k, vT);
  attn_kernel<<<dim3(BB * NHEAD, SS / 128), 256, 0, stream>>>(q, k, vT, ao);
  gemm_o<<<dim3(8, 32), 256, 0, stream>>>(ao, wo, bo, out);
}